// Round 2
// baseline (109.250 us; speedup 1.0000x reference)
//
#include <hip/hip_runtime.h>

// PS-RoI-Align (torchvision ps_roi_align semantics).
// feat: [4, 784, 112, 112] fp32; rois: [K,5]; out: [K, 16, 7, 7] fp32.
// R1: fuse bilinear corner pairs (xl, xl+1) into one float2 load -> 8 gathers/thread.

#define PP 7
#define SR 2
#define SCALEF 0.0625f

constexpr int Cc   = 784;
constexpr int Hh   = 112;
constexpr int Ww   = 112;
constexpr int Cout = 16;

// 4-byte-aligned float2: compiler may emit global_load_dwordx2 (HW supports
// misaligned) or split into two dwords -- correct either way.
typedef float f2v __attribute__((ext_vector_type(2), aligned(4)));

__global__ __launch_bounds__(256) void psroi_align_kernel(
    const float* __restrict__ feat,
    const float* __restrict__ rois,
    float* __restrict__ out,
    int total)
{
    int idx = blockIdx.x * 256 + threadIdx.x;
    if (idx >= total) return;

    int pw = idx % PP;
    int t  = idx / PP;
    int ph = t % PP;
    t /= PP;
    int cout = t % Cout;
    int k    = t / Cout;

    const float* r = rois + (size_t)k * 5;
    int   b  = (int)r[0];
    float x1 = r[1] * SCALEF - 0.5f;
    float y1 = r[2] * SCALEF - 0.5f;
    float roi_w = fmaxf(r[3] * SCALEF - 0.5f - x1, 0.1f);
    float roi_h = fmaxf(r[4] * SCALEF - 0.5f - y1, 0.1f);
    float bsh = roi_h / (float)PP;
    float bsw = roi_w / (float)PP;

    int c = cout * (PP * PP) + ph * PP + pw;
    const float* f = feat + ((size_t)b * Cc + (size_t)c) * (size_t)(Hh * Ww);

    // Precompute x-axis sample descriptors (shared across the 2 y-samples).
    int   xb[SR];      // float2 load base (min(xl, W-2))
    bool  sx[SR];      // xl > xb  (only when xl == W-1)
    float lx[SR], hx[SR];
    bool  vx[SR];
#pragma unroll
    for (int ix = 0; ix < SR; ++ix) {
        float gx = ((float)ix + 0.5f) / (float)SR;
        float x  = x1 + ((float)pw + gx) * bsw;
        vx[ix]   = (x >= -1.0f) && (x <= (float)Ww);
        float xc = fminf(fmaxf(x, 0.0f), (float)(Ww - 1));
        int   xl = (int)xc;                 // xc >= 0, trunc == floor
        xb[ix]   = min(xl, Ww - 2);
        sx[ix]   = (xl > xb[ix]);
        lx[ix]   = xc - (float)xl;
        hx[ix]   = 1.0f - lx[ix];
    }

    float acc = 0.0f;
#pragma unroll
    for (int iy = 0; iy < SR; ++iy) {
        float gy = ((float)iy + 0.5f) / (float)SR;
        float y  = y1 + ((float)ph + gy) * bsh;
        bool  vy = (y >= -1.0f) && (y <= (float)Hh);
        float yc = fminf(fmaxf(y, 0.0f), (float)(Hh - 1));
        int   yl = (int)yc;
        int   yh = min(yl + 1, Hh - 1);
        float ly = yc - (float)yl;
        float hy = 1.0f - ly;

        const float* rowl = f + yl * Ww;
        const float* rowh = f + yh * Ww;

#pragma unroll
        for (int ix = 0; ix < SR; ++ix) {
            // One float2 per row covers both corners:
            //   f[xl] = sx ? a.y : a.x;  f[xh] = a.y (always, given xb=min(xl,W-2))
            f2v a = *(const f2v*)(rowl + xb[ix]);
            f2v d = *(const f2v*)(rowh + xb[ix]);
            float tl = sx[ix] ? a.y : a.x;
            float tr = a.y;
            float bl = sx[ix] ? d.y : d.x;
            float br = d.y;

            float v = hy * (hx[ix] * tl + lx[ix] * tr)
                    + ly * (hx[ix] * bl + lx[ix] * br);
            acc += (vy && vx[ix]) ? v : 0.0f;
        }
    }
    out[idx] = acc * (1.0f / (float)(SR * SR));
}

extern "C" void kernel_launch(void* const* d_in, const int* in_sizes, int n_in,
                              void* d_out, int out_size, void* d_ws, size_t ws_size,
                              hipStream_t stream) {
    const float* feat = (const float*)d_in[0];
    const float* rois = (const float*)d_in[1];
    float* out = (float*)d_out;

    int K = in_sizes[1] / 5;
    int total = K * Cout * PP * PP;
    int blocks = (total + 255) / 256;
    psroi_align_kernel<<<blocks, 256, 0, stream>>>(feat, rois, out, total);
}

// Round 3
// 55.436 us; speedup vs baseline: 1.9707x; 1.9707x over previous
//
#include <hip/hip_runtime.h>

// PS-RoI-Align (torchvision ps_roi_align semantics).
// feat: [4, 784, 112, 112] fp32; rois: [K,5]; out: [K, 16, 7, 7] fp32.
//
// R2: revert R1's float2 gathers (misaligned dwordx2 halved effective HBM BW:
// 59us @6.1TB/s -> 114us @3.2TB/s, same 360MB fetch). Keep R0's scalar-gather
// body; change the DECOMPOSITION to channel-major for L3 reuse:
//   block = (c_chunk, k): 256 consecutive channels of one roi
//   grid ordered c_chunk-major -> all rois' blocks for the same channel
//   window run concurrently; working set ~100MB < 256MB L3, so each feat
//   line is fetched from HBM once per replay instead of once per use.
// Side benefits: roi params are block-uniform (scalar loads), writes stay
// fully coalesced (wave = 64 consecutive c of one k).

#define PP 7
#define SR 2
#define SCALEF 0.0625f

constexpr int Cc   = 784;   // Cout * P * P
constexpr int Hh   = 112;
constexpr int Ww   = 112;
constexpr int CCHUNKS = 4;  // ceil(784/256)

__global__ __launch_bounds__(256) void psroi_align_kernel(
    const float* __restrict__ feat,
    const float* __restrict__ rois,
    float* __restrict__ out,
    int K)
{
    // c_chunk-major grid: blocks 0..K-1 handle channels [0,256) for every k,
    // then [256,512), etc. -> same-channel-window blocks are temporally close.
    int k       = blockIdx.x % K;
    int c_chunk = blockIdx.x / K;
    int c       = c_chunk * 256 + threadIdx.x;
    if (c >= Cc) return;

    int pw   = c % PP;
    int ph   = (c / PP) % PP;
    // cout = c / 49 (implicit in c)

    const float* r = rois + (size_t)k * 5;   // k block-uniform -> scalar loads
    int   b  = (int)r[0];
    float x1 = r[1] * SCALEF - 0.5f;
    float y1 = r[2] * SCALEF - 0.5f;
    float roi_w = fmaxf(r[3] * SCALEF - 0.5f - x1, 0.1f);
    float roi_h = fmaxf(r[4] * SCALEF - 0.5f - y1, 0.1f);
    float bsh = roi_h / (float)PP;
    float bsw = roi_w / (float)PP;

    const float* f = feat + ((size_t)b * Cc + (size_t)c) * (size_t)(Hh * Ww);

    float acc = 0.0f;
#pragma unroll
    for (int iy = 0; iy < SR; ++iy) {
        float gy = ((float)iy + 0.5f) / (float)SR;
        float y  = y1 + ((float)ph + gy) * bsh;
        bool  vy = (y >= -1.0f) && (y <= (float)Hh);
        float yc = fminf(fmaxf(y, 0.0f), (float)(Hh - 1));
        int   yl = (int)floorf(yc);
        int   yh = min(yl + 1, Hh - 1);
        float ly = yc - (float)yl;
        float hy = 1.0f - ly;
#pragma unroll
        for (int ix = 0; ix < SR; ++ix) {
            float gx = ((float)ix + 0.5f) / (float)SR;
            float x  = x1 + ((float)pw + gx) * bsw;
            bool  vx = (x >= -1.0f) && (x <= (float)Ww);
            float xc = fminf(fmaxf(x, 0.0f), (float)(Ww - 1));
            int   xl = (int)floorf(xc);
            int   xh = min(xl + 1, Ww - 1);
            float lx = xc - (float)xl;
            float hx = 1.0f - lx;

            float v = hy * hx * f[yl * Ww + xl]
                    + hy * lx * f[yl * Ww + xh]
                    + ly * hx * f[yh * Ww + xl]
                    + ly * lx * f[yh * Ww + xh];
            acc += (vy && vx) ? v : 0.0f;
        }
    }
    out[(size_t)k * Cc + c] = acc * (1.0f / (float)(SR * SR));
}

extern "C" void kernel_launch(void* const* d_in, const int* in_sizes, int n_in,
                              void* d_out, int out_size, void* d_ws, size_t ws_size,
                              hipStream_t stream) {
    const float* feat = (const float*)d_in[0];
    const float* rois = (const float*)d_in[1];
    float* out = (float*)d_out;

    int K = in_sizes[1] / 5;
    int blocks = CCHUNKS * K;
    psroi_align_kernel<<<blocks, 256, 0, stream>>>(feat, rois, out, K);
}

// Round 4
// 46.993 us; speedup vs baseline: 2.3248x; 1.1797x over previous
//
#include <hip/hip_runtime.h>

// PS-RoI-Align (torchvision ps_roi_align semantics).
// feat: [4, 784, 112, 112] fp32; rois: [K,5]; out: [K, 16, 7, 7] fp32.
//
// R3: plane-resident decomposition. Block = one (b, c) feature plane
// (4*784 = 3136 blocks). Stage the 50 KB plane into LDS via coalesced
// float4 loads (feat read exactly once, sequentially -> ~157 MB HBM),
// then every roi of batch b bilinear-samples from LDS (~5cyc, zero L2
// gather traffic). Thread t handles rois t, t+256, ... and writes
// out[k*784 + c] when the roi's batch matches b.
// Rationale: R0-R2 were bound by 12.8M wave-divergent L2/L3 gather
// requests (55-59us); this moves all gathers into LDS and reduces HBM
// to one sequential sweep (floor ~25us).

#define PP 7
#define SR 2
#define SCALEF 0.0625f

constexpr int Cc    = 784;    // Cout * P * P
constexpr int Hh    = 112;
constexpr int Ww    = 112;
constexpr int PLANE = Hh * Ww;  // 12544 floats = 50176 B

__global__ __launch_bounds__(256) void psroi_plane_kernel(
    const float* __restrict__ feat,
    const float* __restrict__ rois,
    float* __restrict__ out,
    int K)
{
    __shared__ float plane[PLANE];   // 50176 B

    int b = blockIdx.x / Cc;
    int c = blockIdx.x % Cc;

    // ---- stage the (b,c) plane into LDS, coalesced float4 ----
    {
        const float4* src = (const float4*)(feat + ((size_t)b * Cc + c) * (size_t)PLANE);
        float4* dst = (float4*)plane;
        // PLANE/4 = 3136 float4s; 256 threads -> 13 iterations (12 full + tail)
        for (int i = threadIdx.x; i < PLANE / 4; i += 256) dst[i] = src[i];
    }
    __syncthreads();

    int pw = c % PP;
    int ph = (c % (PP * PP)) / PP;

    // ---- each thread processes rois t, t+256, ... ----
    for (int k = threadIdx.x; k < K; k += 256) {
        const float* r = rois + (size_t)k * 5;
        int rb = (int)r[0];
        if (rb != b) continue;

        float x1 = r[1] * SCALEF - 0.5f;
        float y1 = r[2] * SCALEF - 0.5f;
        float roi_w = fmaxf(r[3] * SCALEF - 0.5f - x1, 0.1f);
        float roi_h = fmaxf(r[4] * SCALEF - 0.5f - y1, 0.1f);
        float bsh = roi_h / (float)PP;
        float bsw = roi_w / (float)PP;

        float acc = 0.0f;
#pragma unroll
        for (int iy = 0; iy < SR; ++iy) {
            float gy = ((float)iy + 0.5f) / (float)SR;
            float y  = y1 + ((float)ph + gy) * bsh;
            bool  vy = (y >= -1.0f) && (y <= (float)Hh);
            float yc = fminf(fmaxf(y, 0.0f), (float)(Hh - 1));
            int   yl = (int)yc;              // yc >= 0 -> trunc == floor
            int   yh = min(yl + 1, Hh - 1);
            float ly = yc - (float)yl;
            float hy = 1.0f - ly;
#pragma unroll
            for (int ix = 0; ix < SR; ++ix) {
                float gx = ((float)ix + 0.5f) / (float)SR;
                float x  = x1 + ((float)pw + gx) * bsw;
                bool  vx = (x >= -1.0f) && (x <= (float)Ww);
                float xc = fminf(fmaxf(x, 0.0f), (float)(Ww - 1));
                int   xl = (int)xc;
                int   xh = min(xl + 1, Ww - 1);
                float lx = xc - (float)xl;
                float hx = 1.0f - lx;

                float v = hy * hx * plane[yl * Ww + xl]
                        + hy * lx * plane[yl * Ww + xh]
                        + ly * hx * plane[yh * Ww + xl]
                        + ly * lx * plane[yh * Ww + xh];
                acc += (vy && vx) ? v : 0.0f;
            }
        }
        out[(size_t)k * Cc + c] = acc * (1.0f / (float)(SR * SR));
    }
}

extern "C" void kernel_launch(void* const* d_in, const int* in_sizes, int n_in,
                              void* d_out, int out_size, void* d_ws, size_t ws_size,
                              hipStream_t stream) {
    const float* feat = (const float*)d_in[0];
    const float* rois = (const float*)d_in[1];
    float* out = (float*)d_out;

    int K = in_sizes[1] / 5;
    int feat_total = in_sizes[0];            // N*Cc*H*W
    int N = feat_total / (Cc * PLANE);       // 4
    int blocks = N * Cc;                     // 3136
    psroi_plane_kernel<<<blocks, 256, 0, stream>>>(feat, rois, out, K);
}

// Round 5
// 39.438 us; speedup vs baseline: 2.7702x; 1.1916x over previous
//
#include <hip/hip_runtime.h>

// PS-RoI-Align (torchvision ps_roi_align semantics).
// feat: [4, 784, 112, 112] fp32; rois: [K,5]; out: [K, 16, 7, 7] fp32.
//
// R4: R3's plane-resident decomposition (block = one (b,c) 50KB plane,
// bilinear sampling from LDS), but staging switched from dst[i]=src[i]
// (per-iter load->ds_write dependence, ~1 outstanding req/wave) to async
// __builtin_amdgcn_global_load_lds width=16: each wave issues its 12-13
// 1KB chunks back-to-back, one drain at __syncthreads(). Expect HBM-bound
// (~157MB sequential read floor ~25us).

#define PP 7
#define SR 2
#define SCALEF 0.0625f

constexpr int Cc     = 784;           // Cout * P * P
constexpr int Hh     = 112;
constexpr int Ww     = 112;
constexpr int PLANE  = Hh * Ww;       // 12544 floats = 50176 B
constexpr int CHUNKS = (PLANE * 4) / 1024;  // 49 chunks of 1024 B (64 lanes x 16 B)

__global__ __launch_bounds__(256) void psroi_plane_kernel(
    const float* __restrict__ feat,
    const float* __restrict__ rois,
    float* __restrict__ out,
    int K)
{
    __shared__ float plane[PLANE];   // 50176 B -> 3 blocks/CU

    int b = blockIdx.x / Cc;
    int c = blockIdx.x % Cc;

    // ---- async stage the (b,c) plane into LDS ----
    {
        const float* src = feat + ((size_t)b * Cc + c) * (size_t)PLANE;
        int wave = threadIdx.x >> 6;
        int lane = threadIdx.x & 63;
        // chunk j: global [j*1024 .. j*1024+1023] -> LDS same offset.
        // LDS dest is wave-uniform base; HW adds lane*16. Global src is per-lane.
        for (int j = wave; j < CHUNKS; j += 4) {
            __builtin_amdgcn_global_load_lds(
                (const __attribute__((address_space(1))) void*)(src + j * 256 + lane * 4),
                (__attribute__((address_space(3))) void*)(plane + j * 256),
                16, 0, 0);
        }
    }
    __syncthreads();   // compiler emits s_waitcnt vmcnt(0) before s_barrier

    int pw = c % PP;
    int ph = (c % (PP * PP)) / PP;

    // ---- each thread processes rois t, t+256, ... ----
    for (int k = threadIdx.x; k < K; k += 256) {
        const float* r = rois + (size_t)k * 5;
        int rb = (int)r[0];
        if (rb != b) continue;

        float x1 = r[1] * SCALEF - 0.5f;
        float y1 = r[2] * SCALEF - 0.5f;
        float roi_w = fmaxf(r[3] * SCALEF - 0.5f - x1, 0.1f);
        float roi_h = fmaxf(r[4] * SCALEF - 0.5f - y1, 0.1f);
        float bsh = roi_h / (float)PP;
        float bsw = roi_w / (float)PP;

        float acc = 0.0f;
#pragma unroll
        for (int iy = 0; iy < SR; ++iy) {
            float gy = ((float)iy + 0.5f) / (float)SR;
            float y  = y1 + ((float)ph + gy) * bsh;
            bool  vy = (y >= -1.0f) && (y <= (float)Hh);
            float yc = fminf(fmaxf(y, 0.0f), (float)(Hh - 1));
            int   yl = (int)yc;              // yc >= 0 -> trunc == floor
            int   yh = min(yl + 1, Hh - 1);
            float ly = yc - (float)yl;
            float hy = 1.0f - ly;
#pragma unroll
            for (int ix = 0; ix < SR; ++ix) {
                float gx = ((float)ix + 0.5f) / (float)SR;
                float x  = x1 + ((float)pw + gx) * bsw;
                bool  vx = (x >= -1.0f) && (x <= (float)Ww);
                float xc = fminf(fmaxf(x, 0.0f), (float)(Ww - 1));
                int   xl = (int)xc;
                int   xh = min(xl + 1, Ww - 1);
                float lx = xc - (float)xl;
                float hx = 1.0f - lx;

                float v = hy * hx * plane[yl * Ww + xl]
                        + hy * lx * plane[yl * Ww + xh]
                        + ly * hx * plane[yh * Ww + xl]
                        + ly * lx * plane[yh * Ww + xh];
                acc += (vy && vx) ? v : 0.0f;
            }
        }
        out[(size_t)k * Cc + c] = acc * (1.0f / (float)(SR * SR));
    }
}

extern "C" void kernel_launch(void* const* d_in, const int* in_sizes, int n_in,
                              void* d_out, int out_size, void* d_ws, size_t ws_size,
                              hipStream_t stream) {
    const float* feat = (const float*)d_in[0];
    const float* rois = (const float*)d_in[1];
    float* out = (float*)d_out;

    int K = in_sizes[1] / 5;
    int feat_total = in_sizes[0];            // N*Cc*H*W
    int N = feat_total / (Cc * PLANE);       // 4
    int blocks = N * Cc;                     // 3136
    psroi_plane_kernel<<<blocks, 256, 0, stream>>>(feat, rois, out, K);
}

// Round 6
// 35.136 us; speedup vs baseline: 3.1094x; 1.1224x over previous
//
#include <hip/hip_runtime.h>

// PS-RoI-Align (torchvision ps_roi_align semantics).
// feat: [4, 784, 112, 112] fp32; rois: [K,5]; out: [K, 16, 7, 7] fp32.
//
// R5: persistent double-buffered plane streaming.
//   - 256 persistent blocks (1/CU), 512 threads, 2 x 50KB LDS plane buffers.
//   - Each block grid-strides planes p = bid, bid+256, ... (3136 planes):
//       issue async stage(next plane -> buf[cur^1])   [global_load_lds w=16]
//       compute(cur plane from buf[cur])              [LDS bilinear sampling]
//       __syncthreads()  (drains stage, one barrier/plane)
//       swap
//     -> HBM streaming overlaps compute by construction (T3 2-phase minimum).
//   - roi params parsed ONCE per block into registers (2 rois/thread),
//     not once per plane (R4 re-parsed 1024 rois x 3136 blocks).
// Floor: feat must be read once = 157 MB @ ~6.3 TB/s ~ 25 us.

#define PP 7
#define SR 2
#define SCALEF 0.0625f

constexpr int Cc     = 784;            // Cout * P * P
constexpr int Hh     = 112;
constexpr int Ww     = 112;
constexpr int PLANE  = Hh * Ww;        // 12544 floats = 50176 B
constexpr int CHUNKS = (PLANE * 4) / 1024;  // 49 chunks of 1024 B
constexpr int NBLK   = 256;            // persistent blocks (1 per CU)
constexpr int TPB    = 512;            // 8 waves
constexpr int RPT    = 2;              // rois per thread (K <= 1024)

__global__ __launch_bounds__(TPB) void psroi_persist_kernel(
    const float* __restrict__ feat,
    const float* __restrict__ rois,
    float* __restrict__ out,
    int K, int nplanes)
{
    __shared__ float buf[2][PLANE];    // 100352 B

    int tid  = threadIdx.x;
    int wave = tid >> 6;
    int lane = tid & 63;

    // ---- parse roi params once per block into registers ----
    int   rb[RPT];
    float x1[RPT], y1[RPT], bsh[RPT], bsw[RPT];
#pragma unroll
    for (int j = 0; j < RPT; ++j) {
        int k = tid + j * TPB;
        if (k < K) {
            const float* r = rois + (size_t)k * 5;
            rb[j]  = (int)r[0];
            x1[j]  = r[1] * SCALEF - 0.5f;
            y1[j]  = r[2] * SCALEF - 0.5f;
            float rw = fmaxf(r[3] * SCALEF - 0.5f - x1[j], 0.1f);
            float rh = fmaxf(r[4] * SCALEF - 0.5f - y1[j], 0.1f);
            bsh[j] = rh * (1.0f / (float)PP);
            bsw[j] = rw * (1.0f / (float)PP);
        } else {
            rb[j] = -1;
        }
    }

    // ---- async stage of one plane into buf[bi] ----
    auto stage = [&](int bi, int p) {
        const float* src = feat + (size_t)p * PLANE;
        for (int j = wave; j < CHUNKS; j += TPB / 64) {
            __builtin_amdgcn_global_load_lds(
                (const __attribute__((address_space(1))) void*)(src + j * 256 + lane * 4),
                (__attribute__((address_space(3))) void*)(&buf[bi][j * 256]),
                16, 0, 0);
        }
    };

    // prologue: stage first plane
    int p0 = blockIdx.x;
    stage(0, p0);
    __syncthreads();                   // vmcnt(0) drain + barrier

    int cur = 0;
    for (int p = p0; p < nplanes; p += NBLK) {
        int pn = p + NBLK;
        if (pn < nplanes) stage(cur ^ 1, pn);   // prefetch next plane

        int b  = p / Cc;
        int c  = p % Cc;
        int pw = c % PP;
        int ph = (c % (PP * PP)) / PP;
        const float* pl = buf[cur];

#pragma unroll
        for (int j = 0; j < RPT; ++j) {
            if (rb[j] != b) continue;
            float acc = 0.0f;
#pragma unroll
            for (int iy = 0; iy < SR; ++iy) {
                float gy = ((float)iy + 0.5f) / (float)SR;
                float y  = y1[j] + ((float)ph + gy) * bsh[j];
                bool  vy = (y >= -1.0f) && (y <= (float)Hh);
                float yc = fminf(fmaxf(y, 0.0f), (float)(Hh - 1));
                int   yl = (int)yc;            // yc >= 0 -> trunc == floor
                int   yh = min(yl + 1, Hh - 1);
                float ly = yc - (float)yl;
                float hy = 1.0f - ly;
#pragma unroll
                for (int ix = 0; ix < SR; ++ix) {
                    float gx = ((float)ix + 0.5f) / (float)SR;
                    float x  = x1[j] + ((float)pw + gx) * bsw[j];
                    bool  vx = (x >= -1.0f) && (x <= (float)Ww);
                    float xc = fminf(fmaxf(x, 0.0f), (float)(Ww - 1));
                    int   xl = (int)xc;
                    int   xh = min(xl + 1, Ww - 1);
                    float lx = xc - (float)xl;
                    float hx = 1.0f - lx;

                    float v = hy * hx * pl[yl * Ww + xl]
                            + hy * lx * pl[yl * Ww + xh]
                            + ly * hx * pl[yh * Ww + xl]
                            + ly * lx * pl[yh * Ww + xh];
                    acc += (vy && vx) ? v : 0.0f;
                }
            }
            int k = tid + j * TPB;
            out[(size_t)k * Cc + c] = acc * (1.0f / (float)(SR * SR));
        }

        __syncthreads();               // drain prefetch + protect cur before swap
        cur ^= 1;
    }
}

extern "C" void kernel_launch(void* const* d_in, const int* in_sizes, int n_in,
                              void* d_out, int out_size, void* d_ws, size_t ws_size,
                              hipStream_t stream) {
    const float* feat = (const float*)d_in[0];
    const float* rois = (const float*)d_in[1];
    float* out = (float*)d_out;

    int K = in_sizes[1] / 5;
    int nplanes = in_sizes[0] / PLANE;          // N * Cc = 3136
    psroi_persist_kernel<<<NBLK, TPB, 0, stream>>>(feat, rois, out, K, nplanes);
}